// Round 3
// baseline (1205.463 us; speedup 1.0000x reference)
//
#include <hip/hip_runtime.h>
#include <hip/hip_bf16.h>

// Head-axis-softmax SDPA, B=2 S=2048 N=16 D=64, fp32 in/out.
// softmax over HEADS (n) -> local per (b,q,k). R3: two-pass decomposition.
//   Pass A: rd[b,q,k] = mask ? 1/sum_n exp(s_n) : NaN   (fp32 in d_ws, 33.5 MB)
//   Pass B: per-head, barrier-free k-loop: out += (exp(s)*rd) @ V
// Falls back to the R2 single-kernel if ws_size < 33.6 MB.

#define B_ 2
#define S_ 2048
#define N_ 16
#define D_ 64

typedef __bf16 bf16x8 __attribute__((ext_vector_type(8)));
typedef float  f32x16 __attribute__((ext_vector_type(16)));

// ---------------------------------------------------------------------------
// Pass A: denominator. Block = 1024 thr = 16 waves (wave n = head n).
// 64x64 (q,k) tile per block via 2x2 subtiles of 32x32 MFMA.
// Cross-head sum via LDS float atomics (conflict-free bank pattern).
// ---------------------------------------------------------------------------
__global__ __launch_bounds__(1024) void den_kernel(
    const float* __restrict__ Q, const float* __restrict__ K,
    const int* __restrict__ M, float* __restrict__ RD)
{
    __shared__ float den[64][64];  // 16 KB

    const int tid  = threadIdx.x;
    const int n    = tid >> 6;
    const int lane = tid & 63;
    const int lo   = lane & 31;
    const int hi   = lane >> 5;

    const int k0 = blockIdx.x * 64;
    const int q0 = blockIdx.y * 64;
    const int b  = blockIdx.z;

    float* denf = &den[0][0];
    #pragma unroll
    for (int i = 0; i < 4; ++i) denf[i * 1024 + tid] = 0.0f;
    __syncthreads();

    #pragma unroll
    for (int sq = 0; sq < 2; ++sq) {
        // Q A-frags for rows q0+sq*32+lo, head n
        bf16x8 qf[4];
        {
            const float* qrow = Q + (((size_t)b * S_ + (size_t)(q0 + sq * 32 + lo)) * N_ + n) * D_;
            #pragma unroll
            for (int ks = 0; ks < 4; ++ks) {
                const float* p = qrow + ks * 16 + hi * 8;
                float4 a0 = *(const float4*)(p);
                float4 a1 = *(const float4*)(p + 4);
                bf16x8 f;
                f[0] = (__bf16)a0.x; f[1] = (__bf16)a0.y;
                f[2] = (__bf16)a0.z; f[3] = (__bf16)a0.w;
                f[4] = (__bf16)a1.x; f[5] = (__bf16)a1.y;
                f[6] = (__bf16)a1.z; f[7] = (__bf16)a1.w;
                qf[ks] = f;
            }
        }
        #pragma unroll
        for (int sk = 0; sk < 2; ++sk) {
            f32x16 s = {};
            #pragma unroll
            for (int ks = 0; ks < 4; ++ks) {
                const float* krow = K + (((size_t)b * S_ + (size_t)(k0 + sk * 32 + lo)) * N_ + n) * D_
                                      + ks * 16 + hi * 8;
                float4 a0 = *(const float4*)(krow);
                float4 a1 = *(const float4*)(krow + 4);
                bf16x8 f;
                f[0] = (__bf16)a0.x; f[1] = (__bf16)a0.y;
                f[2] = (__bf16)a0.z; f[3] = (__bf16)a0.w;
                f[4] = (__bf16)a1.x; f[5] = (__bf16)a1.y;
                f[6] = (__bf16)a1.z; f[7] = (__bf16)a1.w;
                s = __builtin_amdgcn_mfma_f32_32x32x16_bf16(qf[ks], f, s, 0, 0, 0);
            }
            #pragma unroll
            for (int r = 0; r < 16; ++r) {
                const int row = (r & 3) + 8 * (r >> 2) + 4 * hi;
                atomicAdd(&den[sq * 32 + row][sk * 32 + lo], __expf(s[r] * 0.125f));
            }
        }
    }
    __syncthreads();

    // rd = mask ? 1/den : NaN, coalesced write
    #pragma unroll
    for (int i = 0; i < 4; ++i) {
        const int c = i * 1024 + tid;
        const int q = c >> 6, k = c & 63;
        const size_t idx = (size_t)b * S_ * S_ + (size_t)(q0 + q) * S_ + (k0 + k);
        const int m = M[idx];
        RD[idx] = m ? (1.0f / den[q][k]) : __builtin_nanf("");
    }
}

// ---------------------------------------------------------------------------
// Pass B: apply. Block = 256 thr = 4 independent waves; one head per block.
// Each wave owns a 256-key strip -> 8 k-iters of 32, NO barriers in the loop.
// P layout transform (C->A) is a wave-local LDS round trip (no __syncthreads).
// ---------------------------------------------------------------------------
#define PK 40

__global__ __launch_bounds__(256, 4) void apply_kernel(
    const float* __restrict__ Q, const float* __restrict__ K,
    const float* __restrict__ V, const float* __restrict__ RD,
    float* __restrict__ O)
{
    __shared__ __align__(16) __bf16 pw[4][32][PK];  // per-wave w-tile, 10 KB
    __shared__ float obuf[32][64];                   // block out reduce, 8 KB

    const int tid  = threadIdx.x;
    const int w    = tid >> 6;
    const int lane = tid & 63;
    const int lo   = lane & 31;
    const int hi   = lane >> 5;

    const int q0 = blockIdx.x * 32;
    const int n  = blockIdx.y;
    const int z  = blockIdx.z;
    const int b  = z >> 1;
    const int ks_half = z & 1;

    float* obf = &obuf[0][0];
    #pragma unroll
    for (int i = 0; i < 8; ++i) obf[i * 256 + tid] = 0.0f;
    __syncthreads();  // obuf zeroed before any wave's atomics

    // Q A-frags (head n, rows q0+lo)
    bf16x8 qf[4];
    {
        const float* qrow = Q + (((size_t)b * S_ + (size_t)(q0 + lo)) * N_ + n) * D_;
        #pragma unroll
        for (int ks = 0; ks < 4; ++ks) {
            const float* p = qrow + ks * 16 + hi * 8;
            float4 a0 = *(const float4*)(p);
            float4 a1 = *(const float4*)(p + 4);
            bf16x8 f;
            f[0] = (__bf16)a0.x; f[1] = (__bf16)a0.y;
            f[2] = (__bf16)a0.z; f[3] = (__bf16)a0.w;
            f[4] = (__bf16)a1.x; f[5] = (__bf16)a1.y;
            f[6] = (__bf16)a1.z; f[7] = (__bf16)a1.w;
            qf[ks] = f;
        }
    }

    f32x16 o0 = {};
    f32x16 o1 = {};

    const int kbase = ks_half * 1024 + w * 256;

    for (int it = 0; it < 8; ++it) {
        const int k0 = kbase + it * 32;

        // QK^T
        f32x16 s = {};
        #pragma unroll
        for (int ks = 0; ks < 4; ++ks) {
            const float* krow = K + (((size_t)b * S_ + (size_t)(k0 + lo)) * N_ + n) * D_
                                  + ks * 16 + hi * 8;
            float4 a0 = *(const float4*)(krow);
            float4 a1 = *(const float4*)(krow + 4);
            bf16x8 f;
            f[0] = (__bf16)a0.x; f[1] = (__bf16)a0.y;
            f[2] = (__bf16)a0.z; f[3] = (__bf16)a0.w;
            f[4] = (__bf16)a1.x; f[5] = (__bf16)a1.y;
            f[6] = (__bf16)a1.z; f[7] = (__bf16)a1.w;
            s = __builtin_amdgcn_mfma_f32_32x32x16_bf16(qf[ks], f, s, 0, 0, 0);
        }

        // V B-frags early (latency overlaps exp/rd/LDS below)
        bf16x8 vf[2][2];
        #pragma unroll
        for (int kstep = 0; kstep < 2; ++kstep) {
            #pragma unroll
            for (int dt = 0; dt < 2; ++dt) {
                bf16x8 f;
                #pragma unroll
                for (int j = 0; j < 8; ++j) {
                    const int key = k0 + kstep * 16 + hi * 8 + j;
                    f[j] = (__bf16)V[(((size_t)b * S_ + key) * N_ + n) * D_ + dt * 32 + lo];
                }
                vf[kstep][dt] = f;
            }
        }

        // w = exp(s)*rd -> wave-local LDS (C-layout scatter)
        #pragma unroll
        for (int r = 0; r < 16; ++r) {
            const int row = (r & 3) + 8 * (r >> 2) + 4 * hi;
            const float rd = RD[(size_t)b * S_ * S_ + (size_t)(q0 + row) * S_ + (k0 + lo)];
            pw[w][row][lo] = (__bf16)(__expf(s[r] * 0.125f) * rd);
        }

        // wave-local C->A transform read (compiler inserts lgkmcnt wait; no barrier)
        #pragma unroll
        for (int kstep = 0; kstep < 2; ++kstep) {
            bf16x8 wf = *(const bf16x8*)&pw[w][lo][kstep * 16 + hi * 8];
            o0 = __builtin_amdgcn_mfma_f32_32x32x16_bf16(wf, vf[kstep][0], o0, 0, 0, 0);
            o1 = __builtin_amdgcn_mfma_f32_32x32x16_bf16(wf, vf[kstep][1], o1, 0, 0, 0);
        }
    }

    // reduce 4 waves' partials in LDS
    #pragma unroll
    for (int r = 0; r < 16; ++r) {
        const int row = (r & 3) + 8 * (r >> 2) + 4 * hi;
        atomicAdd(&obuf[row][lo],      o0[r]);
        atomicAdd(&obuf[row][32 + lo], o1[r]);
    }
    __syncthreads();

    // 2 global atomic adds per output cell (the two ks_half blocks)
    #pragma unroll
    for (int i = 0; i < 8; ++i) {
        const int c = i * 256 + tid;
        const int q = c >> 6, d = c & 63;
        atomicAdd(&O[(((size_t)b * N_ + n) * S_ + (q0 + q)) * D_ + d], obuf[q][d]);
    }
}

// ---------------------------------------------------------------------------
// Fallback (R2 kernel): used when ws_size is too small for rd.
// ---------------------------------------------------------------------------
#define TQ 32
#define TK 32
#define KSPLIT 4
#define ITERS (S_ / TK / KSPLIT)

__global__ __launch_bounds__(1024) void sdpa_headsm_kernel(
    const float* __restrict__ Q, const float* __restrict__ K,
    const float* __restrict__ V, const int* __restrict__ M,
    float* __restrict__ O)
{
    __shared__ __align__(16) __bf16 pbuf[N_][TQ][PK];

    const int tid  = threadIdx.x;
    const int n    = tid >> 6;
    const int lane = tid & 63;
    const int lo   = lane & 31;
    const int hi   = lane >> 5;

    const int qt = blockIdx.x;
    const int b  = blockIdx.y;
    const int kz = blockIdx.z;
    const int q0 = qt * TQ;

    bf16x8 qf[4];
    {
        const float* qrow = Q + (((size_t)b * S_ + (size_t)(q0 + lo)) * N_ + n) * D_;
        #pragma unroll
        for (int ks = 0; ks < 4; ++ks) {
            const float* p = qrow + ks * 16 + hi * 8;
            float4 a0 = *(const float4*)(p);
            float4 a1 = *(const float4*)(p + 4);
            bf16x8 f;
            f[0] = (__bf16)a0.x; f[1] = (__bf16)a0.y;
            f[2] = (__bf16)a0.z; f[3] = (__bf16)a0.w;
            f[4] = (__bf16)a1.x; f[5] = (__bf16)a1.y;
            f[6] = (__bf16)a1.z; f[7] = (__bf16)a1.w;
            qf[ks] = f;
        }
    }

    f32x16 o0 = {};
    f32x16 o1 = {};

    for (int it = 0; it < ITERS; ++it) {
        const int k0 = (kz * ITERS + it) * TK;

        f32x16 s = {};
        #pragma unroll
        for (int ks = 0; ks < 4; ++ks) {
            const float* krow = K + (((size_t)b * S_ + (size_t)(k0 + lo)) * N_ + n) * D_
                                  + ks * 16 + hi * 8;
            float4 a0 = *(const float4*)(krow);
            float4 a1 = *(const float4*)(krow + 4);
            bf16x8 f;
            f[0] = (__bf16)a0.x; f[1] = (__bf16)a0.y;
            f[2] = (__bf16)a0.z; f[3] = (__bf16)a0.w;
            f[4] = (__bf16)a1.x; f[5] = (__bf16)a1.y;
            f[6] = (__bf16)a1.z; f[7] = (__bf16)a1.w;
            s = __builtin_amdgcn_mfma_f32_32x32x16_bf16(qf[ks], f, s, 0, 0, 0);
        }

        bf16x8 vf[2][2];
        #pragma unroll
        for (int kstep = 0; kstep < 2; ++kstep) {
            #pragma unroll
            for (int dt = 0; dt < 2; ++dt) {
                bf16x8 f;
                #pragma unroll
                for (int j = 0; j < 8; ++j) {
                    const int key = k0 + kstep * 16 + hi * 8 + j;
                    f[j] = (__bf16)V[(((size_t)b * S_ + key) * N_ + n) * D_ + dt * 32 + lo];
                }
                vf[kstep][dt] = f;
            }
        }

        #pragma unroll
        for (int r = 0; r < 16; ++r) {
            const int row = (r & 3) + 8 * (r >> 2) + 4 * hi;
            pbuf[n][row][lo] = (__bf16)__expf(s[r] * 0.125f);
        }

        __syncthreads();

        {
            const int tq = tid >> 5;
            const int tk = tid & 31;
            const int m = M[(size_t)b * S_ * S_ + (size_t)(q0 + tq) * S_ + (k0 + tk)];
            float pv[16];
            float sum = 0.f;
            #pragma unroll
            for (int j = 0; j < 16; ++j) { pv[j] = (float)pbuf[j][tq][tk]; sum += pv[j]; }
            const float rd = m ? (1.0f / sum) : __builtin_nanf("");
            #pragma unroll
            for (int j = 0; j < 16; ++j) pbuf[j][tq][tk] = (__bf16)(pv[j] * rd);
        }

        __syncthreads();

        #pragma unroll
        for (int kstep = 0; kstep < 2; ++kstep) {
            const __bf16* wp = &pbuf[n][lo][kstep * 16 + hi * 8];
            bf16x8 wf = *(const bf16x8*)wp;
            o0 = __builtin_amdgcn_mfma_f32_32x32x16_bf16(wf, vf[kstep][0], o0, 0, 0, 0);
            o1 = __builtin_amdgcn_mfma_f32_32x32x16_bf16(wf, vf[kstep][1], o1, 0, 0, 0);
        }

        __syncthreads();
    }

    #pragma unroll
    for (int r = 0; r < 16; ++r) {
        const int row = (r & 3) + 8 * (r >> 2) + 4 * hi;
        const size_t base = (((size_t)b * N_ + n) * S_ + (q0 + row)) * (size_t)D_;
        atomicAdd(&O[base + lo],      o0[r]);
        atomicAdd(&O[base + 32 + lo], o1[r]);
    }
}

extern "C" void kernel_launch(void* const* d_in, const int* in_sizes, int n_in,
                              void* d_out, int out_size, void* d_ws, size_t ws_size,
                              hipStream_t stream) {
    const float* Q = (const float*)d_in[0];
    const float* K = (const float*)d_in[1];
    const float* V = (const float*)d_in[2];
    const int*   M = (const int*)d_in[3];
    float* O = (float*)d_out;

    hipMemsetAsync(d_out, 0, (size_t)out_size * sizeof(float), stream);

    const size_t rd_bytes = (size_t)B_ * S_ * S_ * sizeof(float);  // 33.5 MB
    if (ws_size >= rd_bytes) {
        float* RD = (float*)d_ws;
        den_kernel<<<dim3(S_ / 64, S_ / 64, B_), dim3(1024), 0, stream>>>(Q, K, M, RD);
        apply_kernel<<<dim3(S_ / 32, N_, B_ * 2), dim3(256), 0, stream>>>(Q, K, V, RD, O);
    } else {
        // scratch too small: single-kernel fallback (R2)
        sdpa_headsm_kernel<<<dim3(S_ / TQ, B_, KSPLIT), dim3(1024), 0, stream>>>(Q, K, V, M, O);
    }
}

// Round 4
// 317.388 us; speedup vs baseline: 3.7981x; 3.7981x over previous
//
#include <hip/hip_runtime.h>
#include <hip/hip_bf16.h>

// Head-axis-softmax SDPA, B=2 S=2048 N=16 D=64, fp32 in/out.
// softmax over HEADS (n) -> local per (b,q,k).
// R4: pre-pass repacks inputs to per-head-contiguous bf16 in d_ws:
//   Qb,Kb = [b][n][s][d] bf16, Vt = [b][n][d][s] bf16   (3 x 8 MB)
// so every MFMA fragment load in the main loop is one aligned 16B/lane b128.
// Main kernel = R2 structure (16 waves = 16 heads, TQ=32, TK=32, KSPLIT=4).
// R3's two-pass LDS-atomic variant regressed 3x (16-way atomic contention) — reverted.

#define B_ 2
#define S_ 2048
#define N_ 16
#define D_ 64
#define TQ 32
#define TK 32
#define KSPLIT 4
#define ITERS (S_ / TK / KSPLIT)  // 16 k-tiles per block

typedef __bf16 bf16x4 __attribute__((ext_vector_type(4)));
typedef __bf16 bf16x8 __attribute__((ext_vector_type(8)));
typedef float  f32x16 __attribute__((ext_vector_type(16)));

#define PK 40  // pbuf row stride (bf16): 80 B, 16B-aligned, low-conflict

// ---------------------------------------------------------------------------
// Pre-pass 1: Q,K [b,s,n,d] f32 -> [b,n,s,d] bf16. Both sides coalesced.
// ---------------------------------------------------------------------------
__global__ __launch_bounds__(256) void cvt_qk_kernel(
    const float* __restrict__ Qf, const float* __restrict__ Kf,
    __bf16* __restrict__ Qb, __bf16* __restrict__ Kb)
{
    const int z = blockIdx.z;                  // 0..2B-1: first B -> Q, rest -> K
    const float* src = (z < B_) ? Qf : Kf;
    __bf16*      dst = (z < B_) ? Qb : Kb;
    const int b = (z < B_) ? z : z - B_;
    const int n = blockIdx.y;
    const int t = threadIdx.x;
    const int d4 = (t & 15) * 4;
    const int s  = blockIdx.x * 16 + (t >> 4);

    const float4 v = *(const float4*)&src[(((size_t)b * S_ + s) * N_ + n) * D_ + d4];
    bf16x4 o;
    o[0] = (__bf16)v.x; o[1] = (__bf16)v.y; o[2] = (__bf16)v.z; o[3] = (__bf16)v.w;
    *(bf16x4*)&dst[(((size_t)b * N_ + n) * S_ + s) * D_ + d4] = o;
}

// ---------------------------------------------------------------------------
// Pre-pass 2: V [b,s,n,d] f32 -> [b,n,d,s] bf16 (d<->s transpose via LDS tile).
// ---------------------------------------------------------------------------
__global__ __launch_bounds__(256) void cvt_v_kernel(
    const float* __restrict__ V, __bf16* __restrict__ Vt)
{
    __shared__ __bf16 tile[64][68];  // +4 pad breaks bank aliasing
    const int s0 = blockIdx.x * 64;
    const int n  = blockIdx.y;
    const int b  = blockIdx.z;
    const int t  = threadIdx.x;

    {
        const int d4 = (t & 15) * 4;
        const int sr = t >> 4;
        #pragma unroll
        for (int r = 0; r < 4; ++r) {
            const int s = sr + r * 16;
            const float4 v = *(const float4*)&V[(((size_t)b * S_ + s0 + s) * N_ + n) * D_ + d4];
            tile[s][d4 + 0] = (__bf16)v.x;
            tile[s][d4 + 1] = (__bf16)v.y;
            tile[s][d4 + 2] = (__bf16)v.z;
            tile[s][d4 + 3] = (__bf16)v.w;
        }
    }
    __syncthreads();
    {
        const int s4 = (t & 15) * 4;
        const int dr = t >> 4;
        #pragma unroll
        for (int r = 0; r < 4; ++r) {
            const int d = dr + r * 16;
            bf16x4 o;
            o[0] = tile[s4 + 0][d];
            o[1] = tile[s4 + 1][d];
            o[2] = tile[s4 + 2][d];
            o[3] = tile[s4 + 3][d];
            *(bf16x4*)&Vt[(((size_t)b * N_ + n) * D_ + d) * S_ + s0 + s4] = o;
        }
    }
}

// ---------------------------------------------------------------------------
// Main kernel: R2 structure, bf16 per-head-contiguous inputs.
// Block = 1024 thr = 16 waves (wave n = head n).
// ---------------------------------------------------------------------------
__global__ __launch_bounds__(1024) void sdpa_main_kernel(
    const __bf16* __restrict__ Qb, const __bf16* __restrict__ Kb,
    const __bf16* __restrict__ Vt, const int* __restrict__ M,
    float* __restrict__ O)
{
    __shared__ __align__(16) __bf16 pbuf[N_][TQ][PK];  // 40 KB

    const int tid  = threadIdx.x;
    const int n    = tid >> 6;
    const int lane = tid & 63;
    const int lo   = lane & 31;
    const int hi   = lane >> 5;

    const int q0 = blockIdx.x * TQ;
    const int b  = blockIdx.y;
    const int kz = blockIdx.z;

    const __bf16* Qh = Qb + ((size_t)b * N_ + n) * S_ * D_;  // head-n planes
    const __bf16* Kh = Kb + ((size_t)b * N_ + n) * S_ * D_;
    const __bf16* Vh = Vt + ((size_t)b * N_ + n) * D_ * S_;

    // Q A-frags: one b128 per ks (A: m = lo, k = ks*16 + hi*8 + j)
    bf16x8 qf[4];
    #pragma unroll
    for (int ks = 0; ks < 4; ++ks)
        qf[ks] = *(const bf16x8*)&Qh[(size_t)(q0 + lo) * D_ + ks * 16 + hi * 8];

    f32x16 o0 = {};  // out cols d =  0..31 (C layout)
    f32x16 o1 = {};  // out cols d = 32..63

    for (int it = 0; it < ITERS; ++it) {
        const int k0 = (kz * ITERS + it) * TK;

        // QK^T: B-frag (k = d, col = key=lo): one b128 per ks
        f32x16 s = {};
        #pragma unroll
        for (int ks = 0; ks < 4; ++ks) {
            bf16x8 kf = *(const bf16x8*)&Kh[(size_t)(k0 + lo) * D_ + ks * 16 + hi * 8];
            s = __builtin_amdgcn_mfma_f32_32x32x16_bf16(qf[ks], kf, s, 0, 0, 0);
        }

        // V B-frags (k = key, col = d=dt*32+lo): one b128 each, issued early so
        // their latency overlaps exp + barriers + reduce.
        bf16x8 vf[2][2];
        #pragma unroll
        for (int kstep = 0; kstep < 2; ++kstep)
            #pragma unroll
            for (int dt = 0; dt < 2; ++dt)
                vf[kstep][dt] = *(const bf16x8*)&Vh[(size_t)(dt * 32 + lo) * S_
                                                   + k0 + kstep * 16 + hi * 8];

        // p = exp(s/8) -> pbuf[n][row][col]   (C/D: col=lo, row=(r&3)+8*(r>>2)+4*hi)
        #pragma unroll
        for (int r = 0; r < 16; ++r) {
            const int row = (r & 3) + 8 * (r >> 2) + 4 * hi;
            pbuf[n][row][lo] = (__bf16)__expf(s[r] * 0.125f);
        }

        __syncthreads();  // p complete for all heads

        // cross-head softmax denom + in-place normalize + mask (uniform over n)
        {
            const int tq = tid >> 5;
            const int tk = tid & 31;
            const int m = M[(size_t)b * S_ * S_ + (size_t)(q0 + tq) * S_ + (k0 + tk)];
            float pv[16];
            float sum = 0.f;
            #pragma unroll
            for (int j = 0; j < 16; ++j) { pv[j] = (float)pbuf[j][tq][tk]; sum += pv[j]; }
            // mask==0: ref softmax over all-(-inf) heads -> NaN weights
            const float rd = m ? (1.0f / sum) : __builtin_nanf("");
            #pragma unroll
            for (int j = 0; j < 16; ++j) pbuf[j][tq][tk] = (__bf16)(pv[j] * rd);
        }

        __syncthreads();  // w ready

        // PV: A = W from pbuf (b128)
        #pragma unroll
        for (int kstep = 0; kstep < 2; ++kstep) {
            bf16x8 wf = *(const bf16x8*)&pbuf[n][lo][kstep * 16 + hi * 8];
            o0 = __builtin_amdgcn_mfma_f32_32x32x16_bf16(wf, vf[kstep][0], o0, 0, 0, 0);
            o1 = __builtin_amdgcn_mfma_f32_32x32x16_bf16(wf, vf[kstep][1], o1, 0, 0, 0);
        }

        __syncthreads();  // protect pbuf before next iteration's writes
    }

    // epilogue: k-split partials combine via device-scope atomics
    #pragma unroll
    for (int r = 0; r < 16; ++r) {
        const int row = (r & 3) + 8 * (r >> 2) + 4 * hi;
        const size_t base = (((size_t)b * N_ + n) * S_ + (q0 + row)) * (size_t)D_;
        atomicAdd(&O[base + lo],      o0[r]);
        atomicAdd(&O[base + 32 + lo], o1[r]);
    }
}

// ---------------------------------------------------------------------------
// Fallback (R2 kernel, fp32 inputs): used only if ws is too small.
// ---------------------------------------------------------------------------
__global__ __launch_bounds__(1024) void sdpa_headsm_kernel(
    const float* __restrict__ Q, const float* __restrict__ K,
    const float* __restrict__ V, const int* __restrict__ M,
    float* __restrict__ O)
{
    __shared__ __align__(16) __bf16 pbuf[N_][TQ][PK];

    const int tid  = threadIdx.x;
    const int n    = tid >> 6;
    const int lane = tid & 63;
    const int lo   = lane & 31;
    const int hi   = lane >> 5;

    const int q0 = blockIdx.x * TQ;
    const int b  = blockIdx.y;
    const int kz = blockIdx.z;

    bf16x8 qf[4];
    {
        const float* qrow = Q + (((size_t)b * S_ + (size_t)(q0 + lo)) * N_ + n) * D_;
        #pragma unroll
        for (int ks = 0; ks < 4; ++ks) {
            const float* p = qrow + ks * 16 + hi * 8;
            float4 a0 = *(const float4*)(p);
            float4 a1 = *(const float4*)(p + 4);
            bf16x8 f;
            f[0] = (__bf16)a0.x; f[1] = (__bf16)a0.y;
            f[2] = (__bf16)a0.z; f[3] = (__bf16)a0.w;
            f[4] = (__bf16)a1.x; f[5] = (__bf16)a1.y;
            f[6] = (__bf16)a1.z; f[7] = (__bf16)a1.w;
            qf[ks] = f;
        }
    }

    f32x16 o0 = {};
    f32x16 o1 = {};

    for (int it = 0; it < ITERS; ++it) {
        const int k0 = (kz * ITERS + it) * TK;

        f32x16 s = {};
        #pragma unroll
        for (int ks = 0; ks < 4; ++ks) {
            const float* krow = K + (((size_t)b * S_ + (size_t)(k0 + lo)) * N_ + n) * D_
                                  + ks * 16 + hi * 8;
            float4 a0 = *(const float4*)(krow);
            float4 a1 = *(const float4*)(krow + 4);
            bf16x8 f;
            f[0] = (__bf16)a0.x; f[1] = (__bf16)a0.y;
            f[2] = (__bf16)a0.z; f[3] = (__bf16)a0.w;
            f[4] = (__bf16)a1.x; f[5] = (__bf16)a1.y;
            f[6] = (__bf16)a1.z; f[7] = (__bf16)a1.w;
            s = __builtin_amdgcn_mfma_f32_32x32x16_bf16(qf[ks], f, s, 0, 0, 0);
        }

        bf16x8 vf[2][2];
        #pragma unroll
        for (int kstep = 0; kstep < 2; ++kstep) {
            #pragma unroll
            for (int dt = 0; dt < 2; ++dt) {
                bf16x8 f;
                #pragma unroll
                for (int j = 0; j < 8; ++j) {
                    const int key = k0 + kstep * 16 + hi * 8 + j;
                    f[j] = (__bf16)V[(((size_t)b * S_ + key) * N_ + n) * D_ + dt * 32 + lo];
                }
                vf[kstep][dt] = f;
            }
        }

        #pragma unroll
        for (int r = 0; r < 16; ++r) {
            const int row = (r & 3) + 8 * (r >> 2) + 4 * hi;
            pbuf[n][row][lo] = (__bf16)__expf(s[r] * 0.125f);
        }

        __syncthreads();

        {
            const int tq = tid >> 5;
            const int tk = tid & 31;
            const int m = M[(size_t)b * S_ * S_ + (size_t)(q0 + tq) * S_ + (k0 + tk)];
            float pv[16];
            float sum = 0.f;
            #pragma unroll
            for (int j = 0; j < 16; ++j) { pv[j] = (float)pbuf[j][tq][tk]; sum += pv[j]; }
            const float rd = m ? (1.0f / sum) : __builtin_nanf("");
            #pragma unroll
            for (int j = 0; j < 16; ++j) pbuf[j][tq][tk] = (__bf16)(pv[j] * rd);
        }

        __syncthreads();

        #pragma unroll
        for (int kstep = 0; kstep < 2; ++kstep) {
            bf16x8 wf = *(const bf16x8*)&pbuf[n][lo][kstep * 16 + hi * 8];
            o0 = __builtin_amdgcn_mfma_f32_32x32x16_bf16(wf, vf[kstep][0], o0, 0, 0, 0);
            o1 = __builtin_amdgcn_mfma_f32_32x32x16_bf16(wf, vf[kstep][1], o1, 0, 0, 0);
        }

        __syncthreads();
    }

    #pragma unroll
    for (int r = 0; r < 16; ++r) {
        const int row = (r & 3) + 8 * (r >> 2) + 4 * hi;
        const size_t base = (((size_t)b * N_ + n) * S_ + (q0 + row)) * (size_t)D_;
        atomicAdd(&O[base + lo],      o0[r]);
        atomicAdd(&O[base + 32 + lo], o1[r]);
    }
}

extern "C" void kernel_launch(void* const* d_in, const int* in_sizes, int n_in,
                              void* d_out, int out_size, void* d_ws, size_t ws_size,
                              hipStream_t stream) {
    const float* Q = (const float*)d_in[0];
    const float* K = (const float*)d_in[1];
    const float* V = (const float*)d_in[2];
    const int*   M = (const int*)d_in[3];
    float* O = (float*)d_out;

    hipMemsetAsync(d_out, 0, (size_t)out_size * sizeof(float), stream);

    const size_t per = (size_t)B_ * N_ * S_ * D_;          // 4,194,304 elements
    const size_t need = 3 * per * sizeof(__bf16);          // 24 MB
    if (ws_size >= need) {
        __bf16* Qb = (__bf16*)d_ws;
        __bf16* Kb = Qb + per;
        __bf16* Vt = Kb + per;
        cvt_qk_kernel<<<dim3(S_ / 16, N_, B_ * 2), dim3(256), 0, stream>>>(Q, K, Qb, Kb);
        cvt_v_kernel<<<dim3(S_ / 64, N_, B_), dim3(256), 0, stream>>>(V, Vt);
        sdpa_main_kernel<<<dim3(S_ / TQ, B_, KSPLIT), dim3(1024), 0, stream>>>(Qb, Kb, Vt, M, O);
    } else {
        sdpa_headsm_kernel<<<dim3(S_ / TQ, B_, KSPLIT), dim3(1024), 0, stream>>>(Q, K, V, M, O);
    }
}